// Round 1
// baseline (185.010 us; speedup 1.0000x reference)
//
#include <hip/hip_runtime.h>

#define NN 100000
#define NE 1600000
#define DD 64
#define HIDN 256
#define OD0 20000
#define OD1 1881
#define OD2 27000
#define OUT_TOTAL (OD0 + OD1 + OD2)

// caps (expected: nL1 ~48, nS1 ~51, nL2 ~820, nS2 ~900)
#define MAXL1 8192
#define MAXS1 1024
#define MAXL2 65536
#define MAXS2 8192

__device__ __forceinline__ float wave_sum64(float v) {
#pragma unroll
    for (int off = 32; off >= 1; off >>= 1) v += __shfl_xor(v, off, 64);
    return v;
}

// ---- pass 1: in-degree for all nodes + collect edges whose col in {0,1,2}
__global__ void k_deg_l1(const int* __restrict__ erow, const int* __restrict__ ecol,
                         int* __restrict__ deg, int* __restrict__ cnts, int2* __restrict__ L1) {
    int i = blockIdx.x * blockDim.x + threadIdx.x;
    if (i >= NE) return;
    int c = ecol[i];
    atomicAdd(&deg[c], 1);
    if (c < 3) {
        int r = erow[i];
        int idx = atomicAdd(&cnts[0], 1);
        if (idx < MAXL1) L1[idx] = make_int2(r, c);
    }
}

// dis = rsqrt(deg + 1)  (self-loop included)
__global__ void k_dis(const int* __restrict__ deg, float* __restrict__ dis) {
    int i = blockIdx.x * blockDim.x + threadIdx.x;
    if (i < NN) dis[i] = rsqrtf((float)(deg[i] + 1));
}

// build S1 = {0,1,2} U rows(L1), with slot1 mapping
__global__ void k_s1(int* __restrict__ cnts, const int2* __restrict__ L1,
                     int* __restrict__ flag1, int* __restrict__ slot1, int* __restrict__ S1) {
    int i = blockIdx.x * blockDim.x + threadIdx.x;
    int nl1 = min(cnts[0], MAXL1);
    int n = -1;
    if (i < 3) n = i;
    else if (i - 3 < nl1) n = L1[i - 3].x;
    if (n < 0) return;
    if (atomicExch(&flag1[n], 1) == 0) {
        int s = atomicAdd(&cnts[1], 1);
        if (s < MAXS1) { slot1[n] = s; S1[s] = n; }
    }
}

// ---- pass 2: collect edges whose col in S1
__global__ void k_l2(const int* __restrict__ erow, const int* __restrict__ ecol,
                     const int* __restrict__ flag1, int* __restrict__ cnts, int2* __restrict__ L2) {
    int i = blockIdx.x * blockDim.x + threadIdx.x;
    if (i >= NE) return;
    int c = ecol[i];
    if (flag1[c]) {
        int idx = atomicAdd(&cnts[2], 1);
        if (idx < MAXL2) L2[idx] = make_int2(erow[i], c);
    }
}

// build S2 = rows(L2) U S1 with slot2 mapping
__global__ void k_s2(int* __restrict__ cnts, const int2* __restrict__ L2, const int* __restrict__ S1,
                     int* __restrict__ slot2, int* __restrict__ S2) {
    int i = blockIdx.x * blockDim.x + threadIdx.x;
    int nl2 = min(cnts[2], MAXL2);
    int ns1 = min(cnts[1], MAXS1);
    int n = -1;
    if (i < nl2) n = L2[i].x;
    else if (i - nl2 < ns1) n = S1[i - nl2];
    if (n < 0) return;
    if (atomicCAS(&slot2[n], -1, -2) == -1) {
        int s = atomicAdd(&cnts[3], 1);
        if (s < MAXS2) { slot2[n] = s; S2[s] = n; }
    }
}

// per-node 4-head self-attention over its own 64-dim latent + LayerNorm0
// one wave (64 threads) per node, grid-stride over S2
__global__ void k_x0(const int* __restrict__ cnts, const int* __restrict__ S2,
                     const float* __restrict__ latent,
                     const float* __restrict__ wq, const float* __restrict__ bq,
                     const float* __restrict__ wk, const float* __restrict__ bk,
                     const float* __restrict__ wv, const float* __restrict__ bv,
                     const float* __restrict__ ln0w, const float* __restrict__ ln0b,
                     float* __restrict__ x0c) {
    __shared__ float lx[64], lq[64], lk[64], lv[64], ls[16], lattn[16];
    int t = threadIdx.x;
    int nS2 = min(cnts[3], MAXS2);
    for (int s = blockIdx.x; s < nS2; s += gridDim.x) {
        int n = S2[s];
        lx[t] = latent[n * 64 + t];
        __syncthreads();
        float aq = bq[t], ak = bk[t], av = bv[t];
#pragma unroll
        for (int j = 0; j < 64; j++) {
            float xv = lx[j];
            aq += xv * wq[j * 64 + t];
            ak += xv * wk[j * 64 + t];
            av += xv * wv[j * 64 + t];
        }
        lq[t] = aq; lk[t] = ak; lv[t] = av;
        __syncthreads();
        if (t < 16) {
            int i = t >> 2, j = t & 3;
            float sc = 0.f;
#pragma unroll
            for (int d = 0; d < 16; d++) sc += lq[i * 16 + d] * lk[j * 16 + d];
            ls[t] = sc * 0.25f;  // 1/sqrt(16)
        }
        __syncthreads();
        if (t < 4) {
            float s0 = ls[t * 4], s1 = ls[t * 4 + 1], s2 = ls[t * 4 + 2], s3 = ls[t * 4 + 3];
            float m = fmaxf(fmaxf(s0, s1), fmaxf(s2, s3));
            float e0 = expf(s0 - m), e1 = expf(s1 - m), e2 = expf(s2 - m), e3 = expf(s3 - m);
            float inv = 1.f / (e0 + e1 + e2 + e3);
            lattn[t * 4 + 0] = e0 * inv; lattn[t * 4 + 1] = e1 * inv;
            lattn[t * 4 + 2] = e2 * inv; lattn[t * 4 + 3] = e3 * inv;
        }
        __syncthreads();
        int h = t >> 4, d = t & 15;
        float o = 0.f;
#pragma unroll
        for (int j = 0; j < 4; j++) o += lattn[h * 4 + j] * lv[j * 16 + d];
        // LayerNorm over the wave's 64 values
        float sum = wave_sum64(o), sq = wave_sum64(o * o);
        float mean = sum * (1.f / 64.f);
        float var = sq * (1.f / 64.f) - mean * mean;
        float xh = (o - mean) * rsqrtf(var + 1e-5f);
        x0c[s * 64 + t] = xh * ln0w[t] + ln0b[t];
        __syncthreads();
    }
}

// out[s][t] = sum_j in[s][j] * w[j*64+t]   (no bias; GCN h = x @ w)
__global__ void k_matvec64(const int* __restrict__ cnts, int cntIdx, int cap,
                           const float* __restrict__ xin, const float* __restrict__ w,
                           float* __restrict__ xout) {
    __shared__ float lx[64];
    int t = threadIdx.x;
    int ns = min(cnts[cntIdx], cap);
    for (int s = blockIdx.x; s < ns; s += gridDim.x) {
        lx[t] = xin[s * 64 + t];
        __syncthreads();
        float acc = 0.f;
#pragma unroll
        for (int j = 0; j < 64; j++) acc += lx[j] * w[j * 64 + t];
        xout[s * 64 + t] = acc;
        __syncthreads();
    }
}

// agg1[slot1[c]] += h1[slot2[r]] * dis[r]*dis[c], over L2 edges + S1 self-loops
__global__ void k_agg1(const int* __restrict__ cnts, const int2* __restrict__ L2,
                       const int* __restrict__ S1, const int* __restrict__ slot1,
                       const int* __restrict__ slot2, const float* __restrict__ dis,
                       const float* __restrict__ h1c, float* __restrict__ agg1c) {
    int t = threadIdx.x;
    int nl2 = min(cnts[2], MAXL2);
    int ns1 = min(cnts[1], MAXS1);
    for (int e = blockIdx.x; e < nl2 + ns1; e += gridDim.x) {
        int r, c;
        if (e < nl2) { r = L2[e].x; c = L2[e].y; }
        else { r = c = S1[e - nl2]; }   // self loop
        float wgt = dis[r] * dis[c];
        int sc = slot1[c], sr = slot2[r];
        if (sc < 0 || sc >= MAXS1 || sr < 0 || sr >= MAXS2) continue;
        atomicAdd(&agg1c[sc * 64 + t], h1c[sr * 64 + t] * wgt);
    }
}

// x1 = LN(x0 + agg1 + gcn1_b) at S1 nodes
__global__ void k_x1(const int* __restrict__ cnts, const int* __restrict__ S1,
                     const int* __restrict__ slot2, const float* __restrict__ x0c,
                     const float* __restrict__ agg1c, const float* __restrict__ gb,
                     const float* __restrict__ lnw, const float* __restrict__ lnb,
                     float* __restrict__ x1c) {
    int t = threadIdx.x;
    int ns1 = min(cnts[1], MAXS1);
    for (int s = blockIdx.x; s < ns1; s += gridDim.x) {
        int n = S1[s];
        int s2 = slot2[n];
        if (s2 < 0 || s2 >= MAXS2) continue;
        float v = x0c[s2 * 64 + t] + agg1c[s * 64 + t] + gb[t];
        float sum = wave_sum64(v), sq = wave_sum64(v * v);
        float mean = sum * (1.f / 64.f);
        float var = sq * (1.f / 64.f) - mean * mean;
        x1c[s * 64 + t] = (v - mean) * rsqrtf(var + 1e-5f) * lnw[t] + lnb[t];
    }
}

// agg2[c] += h2[slot1[r]] * dis[r]*dis[c], over L1 edges + {0,1,2} self-loops
__global__ void k_agg2(const int* __restrict__ cnts, const int2* __restrict__ L1,
                       const int* __restrict__ slot1, const float* __restrict__ dis,
                       const float* __restrict__ h2c, float* __restrict__ agg2) {
    int t = threadIdx.x;
    int nl1 = min(cnts[0], MAXL1);
    for (int e = blockIdx.x; e < nl1 + 3; e += gridDim.x) {
        int r, c;
        if (e < nl1) { r = L1[e].x; c = L1[e].y; }
        else { r = c = e - nl1; }   // self loops for nodes 0,1,2
        float wgt = dis[r] * dis[c];
        int sr = slot1[r];
        if (sr < 0 || sr >= MAXS1) continue;
        atomicAdd(&agg2[c * 64 + t], h2c[sr * 64 + t] * wgt);
    }
}

// x2[c] = LN(x1[slot1[c]] + agg2[c] + gcn2_b), c = 0..2
__global__ void k_x2(const int* __restrict__ slot1, const float* __restrict__ x1c,
                     const float* __restrict__ agg2, const float* __restrict__ gb,
                     const float* __restrict__ lnw, const float* __restrict__ lnb,
                     float* __restrict__ x2) {
    int t = threadIdx.x;
    int c = blockIdx.x;
    int s1 = slot1[c];
    if (s1 < 0 || s1 >= MAXS1) return;
    float v = x1c[s1 * 64 + t] + agg2[c * 64 + t] + gb[t];
    float sum = wave_sum64(v), sq = wave_sum64(v * v);
    float mean = sum * (1.f / 64.f);
    float var = sq * (1.f / 64.f) - mean * mean;
    x2[c * 64 + t] = (v - mean) * rsqrtf(var + 1e-5f) * lnw[t] + lnb[t];
}

// hg[i] = relu(x2[i] @ gw1_i + gb1_i)  -- 3 blocks x 256 threads
__global__ void k_gen1(const float* __restrict__ x2,
                       const float* __restrict__ w10, const float* __restrict__ b10,
                       const float* __restrict__ w11, const float* __restrict__ b11,
                       const float* __restrict__ w12, const float* __restrict__ b12,
                       float* __restrict__ hg) {
    __shared__ float lx[64];
    int i = blockIdx.x, k = threadIdx.x;
    const float* w1 = (i == 0) ? w10 : (i == 1) ? w11 : w12;
    const float* b1 = (i == 0) ? b10 : (i == 1) ? b11 : b12;
    if (k < 64) lx[k] = x2[i * 64 + k];
    __syncthreads();
    float acc = b1[k];
#pragma unroll
    for (int j = 0; j < 64; j++) acc += lx[j] * w1[j * 256 + k];
    hg[i * 256 + k] = fmaxf(acc, 0.f);
}

// out[o] = hg[gen] . gw2_gen[:, col] + gb2_gen[col]  -- thread per output column
__global__ void k_out(const float* __restrict__ hg,
                      const float* __restrict__ w20, const float* __restrict__ b20,
                      const float* __restrict__ w21, const float* __restrict__ b21,
                      const float* __restrict__ w22, const float* __restrict__ b22,
                      float* __restrict__ out) {
    __shared__ float lh[3 * 256];
    int t = threadIdx.x;
    lh[t] = hg[t]; lh[t + 256] = hg[t + 256]; lh[t + 512] = hg[t + 512];
    __syncthreads();
    int o = blockIdx.x * blockDim.x + t;
    if (o >= OUT_TOTAL) return;
    int gi, jj, od;
    const float *w2, *b2;
    if (o < OD0)            { gi = 0; jj = o;              od = OD0; w2 = w20; b2 = b20; }
    else if (o < OD0 + OD1) { gi = 1; jj = o - OD0;        od = OD1; w2 = w21; b2 = b21; }
    else                    { gi = 2; jj = o - OD0 - OD1;  od = OD2; w2 = w22; b2 = b22; }
    const float* h = &lh[gi * 256];
    float acc = b2[jj];
#pragma unroll 8
    for (int k = 0; k < 256; k++) acc += h[k] * w2[k * od + jj];
    out[o] = acc;
}

extern "C" void kernel_launch(void* const* d_in, const int* in_sizes, int n_in,
                              void* d_out, int out_size, void* d_ws, size_t ws_size,
                              hipStream_t stream) {
    (void)in_sizes; (void)n_in; (void)out_size; (void)ws_size;
    const float* latent = (const float*)d_in[0];
    const int*   edges  = (const int*)d_in[1];
    const float* wq  = (const float*)d_in[2];
    const float* bq  = (const float*)d_in[3];
    const float* wk  = (const float*)d_in[4];
    const float* bk  = (const float*)d_in[5];
    const float* wv  = (const float*)d_in[6];
    const float* bv  = (const float*)d_in[7];
    const float* ln0w = (const float*)d_in[8];
    const float* ln0b = (const float*)d_in[9];
    const float* g1w  = (const float*)d_in[10];
    const float* g1b  = (const float*)d_in[11];
    const float* ln1w = (const float*)d_in[12];
    const float* ln1b = (const float*)d_in[13];
    const float* g2w  = (const float*)d_in[14];
    const float* g2b  = (const float*)d_in[15];
    const float* ln2w = (const float*)d_in[16];
    const float* ln2b = (const float*)d_in[17];
    const float* gw1_0 = (const float*)d_in[18];
    const float* gb1_0 = (const float*)d_in[19];
    const float* gw2_0 = (const float*)d_in[20];
    const float* gb2_0 = (const float*)d_in[21];
    const float* gw1_1 = (const float*)d_in[22];
    const float* gb1_1 = (const float*)d_in[23];
    const float* gw2_1 = (const float*)d_in[24];
    const float* gb2_1 = (const float*)d_in[25];
    const float* gw1_2 = (const float*)d_in[26];
    const float* gb1_2 = (const float*)d_in[27];
    const float* gw2_2 = (const float*)d_in[28];
    const float* gb2_2 = (const float*)d_in[29];

    // workspace layout (~7.6 MB)
    char* p = (char*)d_ws;
    auto alloc = [&](size_t bytes) { char* r = p; p += (bytes + 255) & ~(size_t)255; return r; };
    int*   cnts  = (int*)alloc(64 * 4);          // [0]=nL1 [1]=nS1 [2]=nL2 [3]=nS2
    int*   deg   = (int*)alloc((size_t)NN * 4);
    float* dis   = (float*)alloc((size_t)NN * 4);
    int*   flag1 = (int*)alloc((size_t)NN * 4);
    int*   slot1 = (int*)alloc((size_t)NN * 4);
    int*   slot2 = (int*)alloc((size_t)NN * 4);
    int2*  L1    = (int2*)alloc((size_t)MAXL1 * 8);
    int*   S1    = (int*)alloc((size_t)MAXS1 * 4);
    int2*  L2    = (int2*)alloc((size_t)MAXL2 * 8);
    int*   S2    = (int*)alloc((size_t)MAXS2 * 4);
    float* x0c   = (float*)alloc((size_t)MAXS2 * 64 * 4);
    float* h1c   = (float*)alloc((size_t)MAXS2 * 64 * 4);
    float* agg1c = (float*)alloc((size_t)MAXS1 * 64 * 4);
    float* x1c   = (float*)alloc((size_t)MAXS1 * 64 * 4);
    float* h2c   = (float*)alloc((size_t)MAXS1 * 64 * 4);
    float* agg2  = (float*)alloc(3 * 64 * 4);
    float* x2    = (float*)alloc(3 * 64 * 4);
    float* hg    = (float*)alloc(3 * HIDN * 4);

    const int* erow = edges;
    const int* ecol = edges + NE;

    hipMemsetAsync(cnts, 0, 64 * 4, stream);
    hipMemsetAsync(deg, 0, (size_t)NN * 4, stream);
    hipMemsetAsync(flag1, 0, (size_t)NN * 4, stream);
    hipMemsetAsync(slot1, 0xFF, (size_t)NN * 4, stream);
    hipMemsetAsync(slot2, 0xFF, (size_t)NN * 4, stream);
    hipMemsetAsync(agg1c, 0, (size_t)MAXS1 * 64 * 4, stream);
    hipMemsetAsync(agg2, 0, 3 * 64 * 4, stream);

    k_deg_l1<<<(NE + 255) / 256, 256, 0, stream>>>(erow, ecol, deg, cnts, L1);
    k_dis<<<(NN + 255) / 256, 256, 0, stream>>>(deg, dis);
    k_s1<<<(MAXL1 + 3 + 255) / 256, 256, 0, stream>>>(cnts, L1, flag1, slot1, S1);
    k_l2<<<(NE + 255) / 256, 256, 0, stream>>>(erow, ecol, flag1, cnts, L2);
    k_s2<<<(MAXL2 + MAXS1 + 255) / 256, 256, 0, stream>>>(cnts, L2, S1, slot2, S2);
    k_x0<<<1024, 64, 0, stream>>>(cnts, S2, latent, wq, bq, wk, bk, wv, bv, ln0w, ln0b, x0c);
    k_matvec64<<<1024, 64, 0, stream>>>(cnts, 3, MAXS2, x0c, g1w, h1c);
    k_agg1<<<512, 64, 0, stream>>>(cnts, L2, S1, slot1, slot2, dis, h1c, agg1c);
    k_x1<<<128, 64, 0, stream>>>(cnts, S1, slot2, x0c, agg1c, g1b, ln1w, ln1b, x1c);
    k_matvec64<<<128, 64, 0, stream>>>(cnts, 1, MAXS1, x1c, g2w, h2c);
    k_agg2<<<64, 64, 0, stream>>>(cnts, L1, slot1, dis, h2c, agg2);
    k_x2<<<3, 64, 0, stream>>>(slot1, x1c, agg2, g2b, ln2w, ln2b, x2);
    k_gen1<<<3, 256, 0, stream>>>(x2, gw1_0, gb1_0, gw1_1, gb1_1, gw1_2, gb1_2, hg);
    k_out<<<(OUT_TOTAL + 255) / 256, 256, 0, stream>>>(hg, gw2_0, gb2_0, gw2_1, gb2_1, gw2_2, gb2_2,
                                                       (float*)d_out);
}

// Round 2
// 84.998 us; speedup vs baseline: 2.1766x; 2.1766x over previous
//
#include <hip/hip_runtime.h>

#define NN 100000
#define NE 1600000
#define HIDN 256
#define OD0 20000
#define OD1 1881
#define OD2 27000
#define OUT_TOTAL (OD0 + OD1 + OD2)

// caps (expected: nL1 ~48, nS1 ~51, nL2 ~820, nS2 ~900)
#define MAXL1 8192
#define MAXS1 1024
#define MAXL2 65536
#define MAXS2 8192

__device__ __forceinline__ float wave_sum64(float v) {
#pragma unroll
    for (int off = 32; off >= 1; off >>= 1) v += __shfl_xor(v, off, 64);
    return v;
}

// ---- scan 1: collect edges whose col in {0,1,2} (no degree pass!)
__global__ void k_scan1(const int* __restrict__ erow, const int* __restrict__ ecol,
                        int* __restrict__ cnts, int2* __restrict__ L1) {
    int i = blockIdx.x * blockDim.x + threadIdx.x;
    if (i >= NE / 4) return;
    int4 c4 = ((const int4*)ecol)[i];
    int cs[4] = {c4.x, c4.y, c4.z, c4.w};
#pragma unroll
    for (int u = 0; u < 4; u++) {
        if (cs[u] < 3) {
            int idx = atomicAdd(&cnts[0], 1);
            if (idx < MAXL1) L1[idx] = make_int2(erow[i * 4 + u], cs[u]);
        }
    }
}

// build S1 = {0,1,2} U rows(L1), with slot1 mapping
__global__ void k_s1(int* __restrict__ cnts, const int2* __restrict__ L1,
                     int* __restrict__ flag1, int* __restrict__ slot1, int* __restrict__ S1) {
    int i = blockIdx.x * blockDim.x + threadIdx.x;
    int nl1 = min(cnts[0], MAXL1);
    int n = -1;
    if (i < 3) n = i;
    else if (i - 3 < nl1) n = L1[i - 3].x;
    if (n < 0) return;
    if (atomicExch(&flag1[n], 1) == 0) {
        int s = atomicAdd(&cnts[1], 1);
        if (s < MAXS1) { slot1[n] = s; S1[s] = n; }
    }
}

// ---- scan 2: collect edges whose col in S1
__global__ void k_scan2(const int* __restrict__ erow, const int* __restrict__ ecol,
                        const int* __restrict__ flag1, int* __restrict__ cnts, int2* __restrict__ L2) {
    int i = blockIdx.x * blockDim.x + threadIdx.x;
    if (i >= NE / 4) return;
    int4 c4 = ((const int4*)ecol)[i];
    int cs[4] = {c4.x, c4.y, c4.z, c4.w};
#pragma unroll
    for (int u = 0; u < 4; u++) {
        if (flag1[cs[u]]) {
            int idx = atomicAdd(&cnts[2], 1);
            if (idx < MAXL2) L2[idx] = make_int2(erow[i * 4 + u], cs[u]);
        }
    }
}

// build S2 = rows(L2) U S1 with slot2 mapping
__global__ void k_s2(int* __restrict__ cnts, const int2* __restrict__ L2, const int* __restrict__ S1,
                     int* __restrict__ slot2, int* __restrict__ S2) {
    int i = blockIdx.x * blockDim.x + threadIdx.x;
    int nl2 = min(cnts[2], MAXL2);
    int ns1 = min(cnts[1], MAXS1);
    int n = -1;
    if (i < nl2) n = L2[i].x;
    else if (i - nl2 < ns1) n = S1[i - nl2];
    if (n < 0) return;
    if (atomicCAS(&slot2[n], -1, -2) == -1) {
        int s = atomicAdd(&cnts[3], 1);
        if (s < MAXS2) { slot2[n] = s; S2[s] = n; }
    }
}

// ---- scan 3: in-degree, but ONLY for nodes in S2 (compacted) -> ~14k atomics not 1.6M
__global__ void k_deg2(const int* __restrict__ ecol, const int* __restrict__ slot2,
                       int* __restrict__ degc) {
    int i = blockIdx.x * blockDim.x + threadIdx.x;
    if (i >= NE / 4) return;
    int4 c4 = ((const int4*)ecol)[i];
    int cs[4] = {c4.x, c4.y, c4.z, c4.w};
#pragma unroll
    for (int u = 0; u < 4; u++) {
        int s = slot2[cs[u]];
        if (s >= 0 && s < MAXS2) atomicAdd(&degc[s], 1);
    }
}

// ---- per-node attention + LN0 + h1 = x0 @ gcn1_w, weights staged in LDS, shfl-only math
#define X0_GRID 192
__global__ __launch_bounds__(256) void k_x0h1(
        const int* __restrict__ cnts, const int* __restrict__ S2,
        const float* __restrict__ latent,
        const float* __restrict__ wq, const float* __restrict__ bq,
        const float* __restrict__ wk, const float* __restrict__ bk,
        const float* __restrict__ wv, const float* __restrict__ bv,
        const float* __restrict__ ln0w, const float* __restrict__ ln0b,
        const float* __restrict__ g1w,
        float* __restrict__ x0c, float* __restrict__ h1c) {
    __shared__ float lw[3 * 4096];   // wq | wk | wv
    __shared__ float lsm[5 * 64];    // bq | bk | bv | ln0w | ln0b
    int t = threadIdx.x;
    {
        const float4* s0 = (const float4*)wq;
        const float4* s1 = (const float4*)wk;
        const float4* s2 = (const float4*)wv;
        float4* d0 = (float4*)&lw[0];
        float4* d1 = (float4*)&lw[4096];
        float4* d2 = (float4*)&lw[8192];
        for (int i = t; i < 1024; i += 256) { d0[i] = s0[i]; d1[i] = s1[i]; d2[i] = s2[i]; }
        if (t < 64) {
            lsm[t] = bq[t]; lsm[64 + t] = bk[t]; lsm[128 + t] = bv[t];
            lsm[192 + t] = ln0w[t]; lsm[256 + t] = ln0b[t];
        }
    }
    __syncthreads();
    int lane = t & 63, w = t >> 6;
    int nS2 = min(cnts[3], MAXS2);
    for (int s = blockIdx.x * 4 + w; s < nS2; s += X0_GRID * 4) {
        int n = S2[s];
        float xv = latent[n * 64 + lane];
        float aq = lsm[lane], ak = lsm[64 + lane], av = lsm[128 + lane];
#pragma unroll
        for (int j = 0; j < 64; j++) {
            float xj = __shfl(xv, j, 64);
            aq = fmaf(xj, lw[j * 64 + lane], aq);
            ak = fmaf(xj, lw[4096 + j * 64 + lane], ak);
            av = fmaf(xj, lw[8192 + j * 64 + lane], av);
        }
        // 4-head attention, all via shfl: lane = h*16+d
        int d = lane & 15;
        float sj[4];
#pragma unroll
        for (int j = 0; j < 4; j++) {
            float kv = __shfl(ak, (j << 4) | d, 64);
            float p = aq * kv;
            p += __shfl_xor(p, 1, 64); p += __shfl_xor(p, 2, 64);
            p += __shfl_xor(p, 4, 64); p += __shfl_xor(p, 8, 64);
            sj[j] = p * 0.25f;   // / sqrt(16)
        }
        float mx = fmaxf(fmaxf(sj[0], sj[1]), fmaxf(sj[2], sj[3]));
        float e0 = expf(sj[0] - mx), e1 = expf(sj[1] - mx);
        float e2 = expf(sj[2] - mx), e3 = expf(sj[3] - mx);
        float inv = 1.f / (e0 + e1 + e2 + e3);
        float at[4] = {e0 * inv, e1 * inv, e2 * inv, e3 * inv};
        float o = 0.f;
#pragma unroll
        for (int j = 0; j < 4; j++) {
            float vv = __shfl(av, (j << 4) | d, 64);
            o = fmaf(at[j], vv, o);
        }
        // LayerNorm0 over the 64 lanes
        float sum = wave_sum64(o), sq = wave_sum64(o * o);
        float mean = sum * (1.f / 64.f);
        float var = sq * (1.f / 64.f) - mean * mean;
        float x0 = (o - mean) * rsqrtf(var + 1e-5f) * lsm[192 + lane] + lsm[256 + lane];
        x0c[s * 64 + lane] = x0;
        // h1 = x0_row @ gcn1_w (row-local, fused)
        float h = 0.f;
#pragma unroll
        for (int j = 0; j < 64; j++) {
            float xj = __shfl(x0, j, 64);
            h = fmaf(xj, g1w[j * 64 + lane], h);
        }
        h1c[s * 64 + lane] = h;
    }
}

// agg1[slot1[c]] += h1[slot2[r]] * dis[r]*dis[c], over L2 edges + S1 self-loops
__global__ void k_agg1(const int* __restrict__ cnts, const int2* __restrict__ L2,
                       const int* __restrict__ S1, const int* __restrict__ slot1,
                       const int* __restrict__ slot2, const int* __restrict__ degc,
                       const float* __restrict__ h1c, float* __restrict__ agg1c) {
    int lane = threadIdx.x;
    int nl2 = min(cnts[2], MAXL2);
    int ns1 = min(cnts[1], MAXS1);
    for (int e = blockIdx.x; e < nl2 + ns1; e += gridDim.x) {
        int r, c;
        if (e < nl2) { r = L2[e].x; c = L2[e].y; }
        else { r = c = S1[e - nl2]; }   // self loop
        int sr2 = slot2[r], sc2 = slot2[c], sc1 = slot1[c];
        if (sr2 < 0 || sr2 >= MAXS2 || sc2 < 0 || sc2 >= MAXS2 || sc1 < 0 || sc1 >= MAXS1) continue;
        float wgt = rsqrtf((float)(degc[sr2] + 1)) * rsqrtf((float)(degc[sc2] + 1));
        atomicAdd(&agg1c[sc1 * 64 + lane], h1c[sr2 * 64 + lane] * wgt);
    }
}

// x1 = LN(x0 + agg1 + gcn1_b) at S1 nodes, fused with h2 = x1 @ gcn2_w
__global__ void k_x1h2(const int* __restrict__ cnts, const int* __restrict__ S1,
                       const int* __restrict__ slot2, const float* __restrict__ x0c,
                       const float* __restrict__ agg1c, const float* __restrict__ gb,
                       const float* __restrict__ lnw, const float* __restrict__ lnb,
                       const float* __restrict__ g2w,
                       float* __restrict__ x1c, float* __restrict__ h2c) {
    int lane = threadIdx.x;
    int ns1 = min(cnts[1], MAXS1);
    for (int s = blockIdx.x; s < ns1; s += gridDim.x) {
        int n = S1[s];
        int s2 = slot2[n];
        if (s2 < 0 || s2 >= MAXS2) continue;
        float v = x0c[s2 * 64 + lane] + agg1c[s * 64 + lane] + gb[lane];
        float sum = wave_sum64(v), sq = wave_sum64(v * v);
        float mean = sum * (1.f / 64.f);
        float var = sq * (1.f / 64.f) - mean * mean;
        float x1 = (v - mean) * rsqrtf(var + 1e-5f) * lnw[lane] + lnb[lane];
        x1c[s * 64 + lane] = x1;
        float h = 0.f;
#pragma unroll
        for (int j = 0; j < 64; j++) {
            float xj = __shfl(x1, j, 64);
            h = fmaf(xj, g2w[j * 64 + lane], h);
        }
        h2c[s * 64 + lane] = h;
    }
}

// fused tail: agg2 (LDS) + x2 = LN(...) + hg = relu(x2 @ gw1 + gb1). one block, 256 threads.
__global__ __launch_bounds__(256) void k_tail(
        const int* __restrict__ cnts, const int2* __restrict__ L1,
        const int* __restrict__ slot1, const int* __restrict__ slot2,
        const int* __restrict__ degc, const float* __restrict__ h2c,
        const float* __restrict__ x1c, const float* __restrict__ g2b,
        const float* __restrict__ lnw, const float* __restrict__ lnb,
        const float* __restrict__ w10, const float* __restrict__ b10,
        const float* __restrict__ w11, const float* __restrict__ b11,
        const float* __restrict__ w12, const float* __restrict__ b12,
        float* __restrict__ hg) {
    __shared__ float aggL[192], lx2[192];
    int t = threadIdx.x, lane = t & 63, w = t >> 6;
    if (t < 192) aggL[t] = 0.f;
    __syncthreads();
    int nl1 = min(cnts[0], MAXL1);
    for (int e = w; e < nl1 + 3; e += 4) {
        int r, c;
        if (e < nl1) { r = L1[e].x; c = L1[e].y; }
        else { r = c = e - nl1; }   // self loops 0,1,2
        int sr1 = slot1[r], sr2 = slot2[r], sc2 = slot2[c];
        if (sr1 < 0 || sr1 >= MAXS1 || sr2 < 0 || sr2 >= MAXS2 || sc2 < 0 || sc2 >= MAXS2) continue;
        float wgt = rsqrtf((float)(degc[sr2] + 1)) * rsqrtf((float)(degc[sc2] + 1));
        atomicAdd(&aggL[c * 64 + lane], h2c[sr1 * 64 + lane] * wgt);
    }
    __syncthreads();
    if (w < 3) {
        int s1 = slot1[w];
        float v = x1c[s1 * 64 + lane] + aggL[w * 64 + lane] + g2b[lane];
        float sum = wave_sum64(v), sq = wave_sum64(v * v);
        float mean = sum * (1.f / 64.f);
        float var = sq * (1.f / 64.f) - mean * mean;
        lx2[w * 64 + lane] = (v - mean) * rsqrtf(var + 1e-5f) * lnw[lane] + lnb[lane];
    }
    __syncthreads();
    const float* W1[3] = {w10, w11, w12};
    const float* B1[3] = {b10, b11, b12};
#pragma unroll
    for (int gi = 0; gi < 3; gi++) {
        float acc = B1[gi][t];
#pragma unroll
        for (int j = 0; j < 64; j++) acc = fmaf(lx2[gi * 64 + j], W1[gi][j * 256 + t], acc);
        hg[gi * 256 + t] = fmaxf(acc, 0.f);
    }
}

// out[o] = hg[gen] . gw2_gen[:, col] + gb2_gen[col]  -- split-K: 4 waves x 64 cols per block
__global__ __launch_bounds__(256) void k_out(const float* __restrict__ hg,
        const float* __restrict__ w20, const float* __restrict__ b20,
        const float* __restrict__ w21, const float* __restrict__ b21,
        const float* __restrict__ w22, const float* __restrict__ b22,
        float* __restrict__ out) {
    __shared__ float lh[768];
    __shared__ float part[256];
    int t = threadIdx.x;
    lh[t] = hg[t]; lh[t + 256] = hg[t + 256]; lh[t + 512] = hg[t + 512];
    __syncthreads();
    int tx = t & 63, ty = t >> 6;
    int o = blockIdx.x * 64 + tx;
    int gi = -1, jj = 0, od = 1;
    const float* w2 = w20;
    if (o < OD0)                 { gi = 0; jj = o;             od = OD0; w2 = w20; }
    else if (o < OD0 + OD1)      { gi = 1; jj = o - OD0;       od = OD1; w2 = w21; }
    else if (o < OUT_TOTAL)      { gi = 2; jj = o - OD0 - OD1; od = OD2; w2 = w22; }
    float acc = 0.f;
    if (gi >= 0) {
        const float* h = &lh[gi * 256 + ty * 64];
        const float* wp = &w2[(size_t)(ty * 64) * od + jj];
#pragma unroll 16
        for (int k = 0; k < 64; k++) acc = fmaf(h[k], wp[(size_t)k * od], acc);
    }
    part[t] = acc;
    __syncthreads();
    if (t < 64 && gi >= 0) {
        float r = part[t] + part[t + 64] + part[t + 128] + part[t + 192];
        const float* b2 = (gi == 0) ? b20 : (gi == 1) ? b21 : b22;
        out[o] = r + b2[jj];
    }
}

extern "C" void kernel_launch(void* const* d_in, const int* in_sizes, int n_in,
                              void* d_out, int out_size, void* d_ws, size_t ws_size,
                              hipStream_t stream) {
    (void)in_sizes; (void)n_in; (void)out_size; (void)ws_size;
    const float* latent = (const float*)d_in[0];
    const int*   edges  = (const int*)d_in[1];
    const float* wq  = (const float*)d_in[2];
    const float* bq  = (const float*)d_in[3];
    const float* wk  = (const float*)d_in[4];
    const float* bk  = (const float*)d_in[5];
    const float* wv  = (const float*)d_in[6];
    const float* bv  = (const float*)d_in[7];
    const float* ln0w = (const float*)d_in[8];
    const float* ln0b = (const float*)d_in[9];
    const float* g1w  = (const float*)d_in[10];
    const float* g1b  = (const float*)d_in[11];
    const float* ln1w = (const float*)d_in[12];
    const float* ln1b = (const float*)d_in[13];
    const float* g2w  = (const float*)d_in[14];
    const float* g2b  = (const float*)d_in[15];
    const float* ln2w = (const float*)d_in[16];
    const float* ln2b = (const float*)d_in[17];
    const float* gw1_0 = (const float*)d_in[18];
    const float* gb1_0 = (const float*)d_in[19];
    const float* gw2_0 = (const float*)d_in[20];
    const float* gb2_0 = (const float*)d_in[21];
    const float* gw1_1 = (const float*)d_in[22];
    const float* gb1_1 = (const float*)d_in[23];
    const float* gw2_1 = (const float*)d_in[24];
    const float* gb2_1 = (const float*)d_in[25];
    const float* gw1_2 = (const float*)d_in[26];
    const float* gb1_2 = (const float*)d_in[27];
    const float* gw2_2 = (const float*)d_in[28];
    const float* gb2_2 = (const float*)d_in[29];

    // workspace layout: [zero region][0xFF region][uninitialized]
    char* p = (char*)d_ws;
    auto alloc = [&](size_t bytes) { char* r = p; p += (bytes + 255) & ~(size_t)255; return r; };
    int*   cnts  = (int*)alloc(64 * 4);          // [0]=nL1 [1]=nS1 [2]=nL2 [3]=nS2
    int*   flag1 = (int*)alloc((size_t)NN * 4);
    int*   degc  = (int*)alloc((size_t)MAXS2 * 4);
    float* agg1c = (float*)alloc((size_t)MAXS1 * 64 * 4);
    char*  zero_end = p;
    int*   slot1 = (int*)alloc((size_t)NN * 4);
    int*   slot2 = (int*)alloc((size_t)NN * 4);
    char*  ff_end = p;
    int2*  L1    = (int2*)alloc((size_t)MAXL1 * 8);
    int*   S1    = (int*)alloc((size_t)MAXS1 * 4);
    int2*  L2    = (int2*)alloc((size_t)MAXL2 * 8);
    int*   S2    = (int*)alloc((size_t)MAXS2 * 4);
    float* x0c   = (float*)alloc((size_t)MAXS2 * 64 * 4);
    float* h1c   = (float*)alloc((size_t)MAXS2 * 64 * 4);
    float* x1c   = (float*)alloc((size_t)MAXS1 * 64 * 4);
    float* h2c   = (float*)alloc((size_t)MAXS1 * 64 * 4);
    float* hg    = (float*)alloc(3 * HIDN * 4);

    const int* erow = edges;
    const int* ecol = edges + NE;

    hipMemsetAsync(cnts, 0, (size_t)(zero_end - (char*)cnts), stream);
    hipMemsetAsync(slot1, 0xFF, (size_t)(ff_end - (char*)slot1), stream);

    const int SCAN_GRID = (NE / 4 + 255) / 256;
    k_scan1<<<SCAN_GRID, 256, 0, stream>>>(erow, ecol, cnts, L1);
    k_s1<<<(MAXL1 + 3 + 255) / 256, 256, 0, stream>>>(cnts, L1, flag1, slot1, S1);
    k_scan2<<<SCAN_GRID, 256, 0, stream>>>(erow, ecol, flag1, cnts, L2);
    k_s2<<<(MAXL2 + MAXS1 + 255) / 256, 256, 0, stream>>>(cnts, L2, S1, slot2, S2);
    k_deg2<<<SCAN_GRID, 256, 0, stream>>>(ecol, slot2, degc);
    k_x0h1<<<X0_GRID, 256, 0, stream>>>(cnts, S2, latent, wq, bq, wk, bk, wv, bv,
                                        ln0w, ln0b, g1w, x0c, h1c);
    k_agg1<<<256, 64, 0, stream>>>(cnts, L2, S1, slot1, slot2, degc, h1c, agg1c);
    k_x1h2<<<64, 64, 0, stream>>>(cnts, S1, slot2, x0c, agg1c, g1b, ln1w, ln1b, g2w, x1c, h2c);
    k_tail<<<1, 256, 0, stream>>>(cnts, L1, slot1, slot2, degc, h2c, x1c, g2b, ln2w, ln2b,
                                  gw1_0, gb1_0, gw1_1, gb1_1, gw1_2, gb1_2, hg);
    k_out<<<(OUT_TOTAL + 63) / 64, 256, 0, stream>>>(hg, gw2_0, gb2_0, gw2_1, gb2_1,
                                                     gw2_2, gb2_2, (float*)d_out);
}

// Round 3
// 84.264 us; speedup vs baseline: 2.1956x; 1.0087x over previous
//
#include <hip/hip_runtime.h>

#define NN 100000
#define NE 1600000
#define HIDN 256
#define OD0 20000
#define OD1 1881
#define OD2 27000
#define OUT_TOTAL (OD0 + OD1 + OD2)

// caps (expected: nL1 ~48, nS1 ~51, nL2 ~820, nS2 ~900)
#define MAXL1 8192
#define MAXS1 1024
#define MAXL2 65536
#define MAXS2 8192

__device__ __forceinline__ float wave_sum64(float v) {
#pragma unroll
    for (int off = 32; off >= 1; off >>= 1) v += __shfl_xor(v, off, 64);
    return v;
}

// ---- init: flag1=0 (25000 int4), slot2=-1 (25000 int4), agg1c=0 (16384 int4),
//            degc=0 (2048 int4), cnts=0 (16 int4). total 68448 int4.
// replaces hipMemsetAsync: runtime fillBuffer took ~40us per call (!)
__global__ void k_init(int* __restrict__ flag1, int* __restrict__ slot2,
                       float* __restrict__ agg1c, int* __restrict__ degc,
                       int* __restrict__ cnts) {
    int i = blockIdx.x * blockDim.x + threadIdx.x;
    int4 z = make_int4(0, 0, 0, 0);
    int4 m = make_int4(-1, -1, -1, -1);
    if (i < 25000)       ((int4*)flag1)[i] = z;
    else if (i < 50000)  ((int4*)slot2)[i - 25000] = m;
    else if (i < 66384)  ((int4*)agg1c)[i - 50000] = z;
    else if (i < 68432)  ((int4*)degc)[i - 66384] = z;
    else if (i < 68448)  ((int4*)cnts)[i - 68432] = z;
}

// ---- scan 1: collect edges whose col in {0,1,2}
__global__ void k_scan1(const int* __restrict__ erow, const int* __restrict__ ecol,
                        int* __restrict__ cnts, int2* __restrict__ L1) {
    int i = blockIdx.x * blockDim.x + threadIdx.x;
    if (i >= NE / 4) return;
    int4 c4 = ((const int4*)ecol)[i];
    int cs[4] = {c4.x, c4.y, c4.z, c4.w};
#pragma unroll
    for (int u = 0; u < 4; u++) {
        if (cs[u] < 3) {
            int idx = atomicAdd(&cnts[0], 1);
            if (idx < MAXL1) L1[idx] = make_int2(erow[i * 4 + u], cs[u]);
        }
    }
}

// build S1 = {0,1,2} U rows(L1), with slot1 mapping
// NOTE: slot1 needs no init — it is only read at nodes that are provably in S1.
__global__ void k_s1(int* __restrict__ cnts, const int2* __restrict__ L1,
                     int* __restrict__ flag1, int* __restrict__ slot1, int* __restrict__ S1) {
    int i = blockIdx.x * blockDim.x + threadIdx.x;
    int nl1 = min(cnts[0], MAXL1);
    int n = -1;
    if (i < 3) n = i;
    else if (i - 3 < nl1) n = L1[i - 3].x;
    if (n < 0) return;
    if (atomicExch(&flag1[n], 1) == 0) {
        int s = atomicAdd(&cnts[1], 1);
        if (s < MAXS1) { slot1[n] = s; S1[s] = n; }
    }
}

// ---- scan 2: collect edges whose col in S1
__global__ void k_scan2(const int* __restrict__ erow, const int* __restrict__ ecol,
                        const int* __restrict__ flag1, int* __restrict__ cnts, int2* __restrict__ L2) {
    int i = blockIdx.x * blockDim.x + threadIdx.x;
    if (i >= NE / 4) return;
    int4 c4 = ((const int4*)ecol)[i];
    int cs[4] = {c4.x, c4.y, c4.z, c4.w};
#pragma unroll
    for (int u = 0; u < 4; u++) {
        if (flag1[cs[u]]) {
            int idx = atomicAdd(&cnts[2], 1);
            if (idx < MAXL2) L2[idx] = make_int2(erow[i * 4 + u], cs[u]);
        }
    }
}

// build S2 = rows(L2) U S1 with slot2 mapping
__global__ void k_s2(int* __restrict__ cnts, const int2* __restrict__ L2, const int* __restrict__ S1,
                     int* __restrict__ slot2, int* __restrict__ S2) {
    int i = blockIdx.x * blockDim.x + threadIdx.x;
    int nl2 = min(cnts[2], MAXL2);
    int ns1 = min(cnts[1], MAXS1);
    int n = -1;
    if (i < nl2) n = L2[i].x;
    else if (i - nl2 < ns1) n = S1[i - nl2];
    if (n < 0) return;
    if (atomicCAS(&slot2[n], -1, -2) == -1) {
        int s = atomicAdd(&cnts[3], 1);
        if (s < MAXS2) { slot2[n] = s; S2[s] = n; }
    }
}

// ---- scan 3: in-degree, ONLY for nodes in S2 (compacted)
__global__ void k_deg2(const int* __restrict__ ecol, const int* __restrict__ slot2,
                       int* __restrict__ degc) {
    int i = blockIdx.x * blockDim.x + threadIdx.x;
    if (i >= NE / 4) return;
    int4 c4 = ((const int4*)ecol)[i];
    int cs[4] = {c4.x, c4.y, c4.z, c4.w};
#pragma unroll
    for (int u = 0; u < 4; u++) {
        int s = slot2[cs[u]];
        if (s >= 0 && s < MAXS2) atomicAdd(&degc[s], 1);
    }
}

// ---- per-node attention + LN0 + h1 = x0 @ gcn1_w, weights staged in LDS, shfl-only math
#define X0_GRID 192
__global__ __launch_bounds__(256) void k_x0h1(
        const int* __restrict__ cnts, const int* __restrict__ S2,
        const float* __restrict__ latent,
        const float* __restrict__ wq, const float* __restrict__ bq,
        const float* __restrict__ wk, const float* __restrict__ bk,
        const float* __restrict__ wv, const float* __restrict__ bv,
        const float* __restrict__ ln0w, const float* __restrict__ ln0b,
        const float* __restrict__ g1w,
        float* __restrict__ x0c, float* __restrict__ h1c) {
    __shared__ float lw[3 * 4096];   // wq | wk | wv
    __shared__ float lsm[5 * 64];    // bq | bk | bv | ln0w | ln0b
    int t = threadIdx.x;
    {
        const float4* s0 = (const float4*)wq;
        const float4* s1 = (const float4*)wk;
        const float4* s2 = (const float4*)wv;
        float4* d0 = (float4*)&lw[0];
        float4* d1 = (float4*)&lw[4096];
        float4* d2 = (float4*)&lw[8192];
        for (int i = t; i < 1024; i += 256) { d0[i] = s0[i]; d1[i] = s1[i]; d2[i] = s2[i]; }
        if (t < 64) {
            lsm[t] = bq[t]; lsm[64 + t] = bk[t]; lsm[128 + t] = bv[t];
            lsm[192 + t] = ln0w[t]; lsm[256 + t] = ln0b[t];
        }
    }
    __syncthreads();
    int lane = t & 63, w = t >> 6;
    int nS2 = min(cnts[3], MAXS2);
    for (int s = blockIdx.x * 4 + w; s < nS2; s += X0_GRID * 4) {
        int n = S2[s];
        float xv = latent[n * 64 + lane];
        float aq = lsm[lane], ak = lsm[64 + lane], av = lsm[128 + lane];
#pragma unroll
        for (int j = 0; j < 64; j++) {
            float xj = __shfl(xv, j, 64);
            aq = fmaf(xj, lw[j * 64 + lane], aq);
            ak = fmaf(xj, lw[4096 + j * 64 + lane], ak);
            av = fmaf(xj, lw[8192 + j * 64 + lane], av);
        }
        // 4-head attention, all via shfl: lane = h*16+d
        int d = lane & 15;
        float sj[4];
#pragma unroll
        for (int j = 0; j < 4; j++) {
            float kv = __shfl(ak, (j << 4) | d, 64);
            float p = aq * kv;
            p += __shfl_xor(p, 1, 64); p += __shfl_xor(p, 2, 64);
            p += __shfl_xor(p, 4, 64); p += __shfl_xor(p, 8, 64);
            sj[j] = p * 0.25f;   // / sqrt(16)
        }
        float mx = fmaxf(fmaxf(sj[0], sj[1]), fmaxf(sj[2], sj[3]));
        float e0 = expf(sj[0] - mx), e1 = expf(sj[1] - mx);
        float e2 = expf(sj[2] - mx), e3 = expf(sj[3] - mx);
        float inv = 1.f / (e0 + e1 + e2 + e3);
        float at[4] = {e0 * inv, e1 * inv, e2 * inv, e3 * inv};
        float o = 0.f;
#pragma unroll
        for (int j = 0; j < 4; j++) {
            float vv = __shfl(av, (j << 4) | d, 64);
            o = fmaf(at[j], vv, o);
        }
        // LayerNorm0 over the 64 lanes
        float sum = wave_sum64(o), sq = wave_sum64(o * o);
        float mean = sum * (1.f / 64.f);
        float var = sq * (1.f / 64.f) - mean * mean;
        float x0 = (o - mean) * rsqrtf(var + 1e-5f) * lsm[192 + lane] + lsm[256 + lane];
        x0c[s * 64 + lane] = x0;
        // h1 = x0_row @ gcn1_w (row-local, fused)
        float h = 0.f;
#pragma unroll
        for (int j = 0; j < 64; j++) {
            float xj = __shfl(x0, j, 64);
            h = fmaf(xj, g1w[j * 64 + lane], h);
        }
        h1c[s * 64 + lane] = h;
    }
}

// agg1[slot1[c]] += h1[slot2[r]] * dis[r]*dis[c], over L2 edges + S1 self-loops
__global__ void k_agg1(const int* __restrict__ cnts, const int2* __restrict__ L2,
                       const int* __restrict__ S1, const int* __restrict__ slot1,
                       const int* __restrict__ slot2, const int* __restrict__ degc,
                       const float* __restrict__ h1c, float* __restrict__ agg1c) {
    int lane = threadIdx.x;
    int nl2 = min(cnts[2], MAXL2);
    int ns1 = min(cnts[1], MAXS1);
    for (int e = blockIdx.x; e < nl2 + ns1; e += gridDim.x) {
        int r, c;
        if (e < nl2) { r = L2[e].x; c = L2[e].y; }
        else { r = c = S1[e - nl2]; }   // self loop
        int sr2 = slot2[r], sc2 = slot2[c], sc1 = slot1[c];
        if (sr2 < 0 || sr2 >= MAXS2 || sc2 < 0 || sc2 >= MAXS2 || sc1 < 0 || sc1 >= MAXS1) continue;
        float wgt = rsqrtf((float)(degc[sr2] + 1)) * rsqrtf((float)(degc[sc2] + 1));
        atomicAdd(&agg1c[sc1 * 64 + lane], h1c[sr2 * 64 + lane] * wgt);
    }
}

// x1 = LN(x0 + agg1 + gcn1_b) at S1 nodes, fused with h2 = x1 @ gcn2_w
__global__ void k_x1h2(const int* __restrict__ cnts, const int* __restrict__ S1,
                       const int* __restrict__ slot2, const float* __restrict__ x0c,
                       const float* __restrict__ agg1c, const float* __restrict__ gb,
                       const float* __restrict__ lnw, const float* __restrict__ lnb,
                       const float* __restrict__ g2w,
                       float* __restrict__ x1c, float* __restrict__ h2c) {
    int lane = threadIdx.x;
    int ns1 = min(cnts[1], MAXS1);
    for (int s = blockIdx.x; s < ns1; s += gridDim.x) {
        int n = S1[s];
        int s2 = slot2[n];
        if (s2 < 0 || s2 >= MAXS2) continue;
        float v = x0c[s2 * 64 + lane] + agg1c[s * 64 + lane] + gb[lane];
        float sum = wave_sum64(v), sq = wave_sum64(v * v);
        float mean = sum * (1.f / 64.f);
        float var = sq * (1.f / 64.f) - mean * mean;
        float x1 = (v - mean) * rsqrtf(var + 1e-5f) * lnw[lane] + lnb[lane];
        x1c[s * 64 + lane] = x1;
        float h = 0.f;
#pragma unroll
        for (int j = 0; j < 64; j++) {
            float xj = __shfl(x1, j, 64);
            h = fmaf(xj, g2w[j * 64 + lane], h);
        }
        h2c[s * 64 + lane] = h;
    }
}

// fused tail: agg2 (LDS) + x2 = LN(...) + hg = relu(x2 @ gw1 + gb1). one block, 256 threads.
__global__ __launch_bounds__(256) void k_tail(
        const int* __restrict__ cnts, const int2* __restrict__ L1,
        const int* __restrict__ slot1, const int* __restrict__ slot2,
        const int* __restrict__ degc, const float* __restrict__ h2c,
        const float* __restrict__ x1c, const float* __restrict__ g2b,
        const float* __restrict__ lnw, const float* __restrict__ lnb,
        const float* __restrict__ w10, const float* __restrict__ b10,
        const float* __restrict__ w11, const float* __restrict__ b11,
        const float* __restrict__ w12, const float* __restrict__ b12,
        float* __restrict__ hg) {
    __shared__ float aggL[192], lx2[192];
    int t = threadIdx.x, lane = t & 63, w = t >> 6;
    if (t < 192) aggL[t] = 0.f;
    __syncthreads();
    int nl1 = min(cnts[0], MAXL1);
    for (int e = w; e < nl1 + 3; e += 4) {
        int r, c;
        if (e < nl1) { r = L1[e].x; c = L1[e].y; }
        else { r = c = e - nl1; }   // self loops 0,1,2
        int sr1 = slot1[r], sr2 = slot2[r], sc2 = slot2[c];
        if (sr1 < 0 || sr1 >= MAXS1 || sr2 < 0 || sr2 >= MAXS2 || sc2 < 0 || sc2 >= MAXS2) continue;
        float wgt = rsqrtf((float)(degc[sr2] + 1)) * rsqrtf((float)(degc[sc2] + 1));
        atomicAdd(&aggL[c * 64 + lane], h2c[sr1 * 64 + lane] * wgt);
    }
    __syncthreads();
    if (w < 3) {
        int s1 = slot1[w];
        float v = x1c[s1 * 64 + lane] + aggL[w * 64 + lane] + g2b[lane];
        float sum = wave_sum64(v), sq = wave_sum64(v * v);
        float mean = sum * (1.f / 64.f);
        float var = sq * (1.f / 64.f) - mean * mean;
        lx2[w * 64 + lane] = (v - mean) * rsqrtf(var + 1e-5f) * lnw[lane] + lnb[lane];
    }
    __syncthreads();
    const float* W1[3] = {w10, w11, w12};
    const float* B1[3] = {b10, b11, b12};
#pragma unroll
    for (int gi = 0; gi < 3; gi++) {
        float acc = B1[gi][t];
#pragma unroll
        for (int j = 0; j < 64; j++) acc = fmaf(lx2[gi * 64 + j], W1[gi][j * 256 + t], acc);
        hg[gi * 256 + t] = fmaxf(acc, 0.f);
    }
}

// out[o] = hg[gen] . gw2_gen[:, col] + gb2_gen[col]  -- split-K: 4 waves x 64 cols per block
__global__ __launch_bounds__(256) void k_out(const float* __restrict__ hg,
        const float* __restrict__ w20, const float* __restrict__ b20,
        const float* __restrict__ w21, const float* __restrict__ b21,
        const float* __restrict__ w22, const float* __restrict__ b22,
        float* __restrict__ out) {
    __shared__ float lh[768];
    __shared__ float part[256];
    int t = threadIdx.x;
    lh[t] = hg[t]; lh[t + 256] = hg[t + 256]; lh[t + 512] = hg[t + 512];
    __syncthreads();
    int tx = t & 63, ty = t >> 6;
    int o = blockIdx.x * 64 + tx;
    int gi = -1, jj = 0, od = 1;
    const float* w2 = w20;
    if (o < OD0)                 { gi = 0; jj = o;             od = OD0; w2 = w20; }
    else if (o < OD0 + OD1)      { gi = 1; jj = o - OD0;       od = OD1; w2 = w21; }
    else if (o < OUT_TOTAL)      { gi = 2; jj = o - OD0 - OD1; od = OD2; w2 = w22; }
    float acc = 0.f;
    if (gi >= 0) {
        const float* h = &lh[gi * 256 + ty * 64];
        const float* wp = &w2[(size_t)(ty * 64) * od + jj];
#pragma unroll 16
        for (int k = 0; k < 64; k++) acc = fmaf(h[k], wp[(size_t)k * od], acc);
    }
    part[t] = acc;
    __syncthreads();
    if (t < 64 && gi >= 0) {
        float r = part[t] + part[t + 64] + part[t + 128] + part[t + 192];
        const float* b2 = (gi == 0) ? b20 : (gi == 1) ? b21 : b22;
        out[o] = r + b2[jj];
    }
}

extern "C" void kernel_launch(void* const* d_in, const int* in_sizes, int n_in,
                              void* d_out, int out_size, void* d_ws, size_t ws_size,
                              hipStream_t stream) {
    (void)in_sizes; (void)n_in; (void)out_size; (void)ws_size;
    const float* latent = (const float*)d_in[0];
    const int*   edges  = (const int*)d_in[1];
    const float* wq  = (const float*)d_in[2];
    const float* bq  = (const float*)d_in[3];
    const float* wk  = (const float*)d_in[4];
    const float* bk  = (const float*)d_in[5];
    const float* wv  = (const float*)d_in[6];
    const float* bv  = (const float*)d_in[7];
    const float* ln0w = (const float*)d_in[8];
    const float* ln0b = (const float*)d_in[9];
    const float* g1w  = (const float*)d_in[10];
    const float* g1b  = (const float*)d_in[11];
    const float* ln1w = (const float*)d_in[12];
    const float* ln1b = (const float*)d_in[13];
    const float* g2w  = (const float*)d_in[14];
    const float* g2b  = (const float*)d_in[15];
    const float* ln2w = (const float*)d_in[16];
    const float* ln2b = (const float*)d_in[17];
    const float* gw1_0 = (const float*)d_in[18];
    const float* gb1_0 = (const float*)d_in[19];
    const float* gw2_0 = (const float*)d_in[20];
    const float* gb2_0 = (const float*)d_in[21];
    const float* gw1_1 = (const float*)d_in[22];
    const float* gb1_1 = (const float*)d_in[23];
    const float* gw2_1 = (const float*)d_in[24];
    const float* gb2_1 = (const float*)d_in[25];
    const float* gw1_2 = (const float*)d_in[26];
    const float* gb1_2 = (const float*)d_in[27];
    const float* gw2_2 = (const float*)d_in[28];
    const float* gb2_2 = (const float*)d_in[29];

    // workspace layout
    char* p = (char*)d_ws;
    auto alloc = [&](size_t bytes) { char* r = p; p += (bytes + 255) & ~(size_t)255; return r; };
    int*   cnts  = (int*)alloc(64 * 4);          // [0]=nL1 [1]=nS1 [2]=nL2 [3]=nS2
    int*   flag1 = (int*)alloc((size_t)NN * 4);
    int*   degc  = (int*)alloc((size_t)MAXS2 * 4);
    float* agg1c = (float*)alloc((size_t)MAXS1 * 64 * 4);
    int*   slot1 = (int*)alloc((size_t)NN * 4);  // no init needed
    int*   slot2 = (int*)alloc((size_t)NN * 4);  // init to -1 by k_init
    int2*  L1    = (int2*)alloc((size_t)MAXL1 * 8);
    int*   S1    = (int*)alloc((size_t)MAXS1 * 4);
    int2*  L2    = (int2*)alloc((size_t)MAXL2 * 8);
    int*   S2    = (int*)alloc((size_t)MAXS2 * 4);
    float* x0c   = (float*)alloc((size_t)MAXS2 * 64 * 4);
    float* h1c   = (float*)alloc((size_t)MAXS2 * 64 * 4);
    float* x1c   = (float*)alloc((size_t)MAXS1 * 64 * 4);
    float* h2c   = (float*)alloc((size_t)MAXS1 * 64 * 4);
    float* hg    = (float*)alloc(3 * HIDN * 4);

    const int* erow = edges;
    const int* ecol = edges + NE;

    const int SCAN_GRID = (NE / 4 + 255) / 256;
    k_init<<<(68448 + 255) / 256, 256, 0, stream>>>(flag1, slot2, agg1c, degc, cnts);
    k_scan1<<<SCAN_GRID, 256, 0, stream>>>(erow, ecol, cnts, L1);
    k_s1<<<(MAXL1 + 3 + 255) / 256, 256, 0, stream>>>(cnts, L1, flag1, slot1, S1);
    k_scan2<<<SCAN_GRID, 256, 0, stream>>>(erow, ecol, flag1, cnts, L2);
    k_s2<<<(MAXL2 + MAXS1 + 255) / 256, 256, 0, stream>>>(cnts, L2, S1, slot2, S2);
    k_deg2<<<SCAN_GRID, 256, 0, stream>>>(ecol, slot2, degc);
    k_x0h1<<<X0_GRID, 256, 0, stream>>>(cnts, S2, latent, wq, bq, wk, bk, wv, bv,
                                        ln0w, ln0b, g1w, x0c, h1c);
    k_agg1<<<256, 64, 0, stream>>>(cnts, L2, S1, slot1, slot2, degc, h1c, agg1c);
    k_x1h2<<<64, 64, 0, stream>>>(cnts, S1, slot2, x0c, agg1c, g1b, ln1w, ln1b, g2w, x1c, h2c);
    k_tail<<<1, 256, 0, stream>>>(cnts, L1, slot1, slot2, degc, h2c, x1c, g2b, ln2w, ln2b,
                                  gw1_0, gb1_0, gw1_1, gb1_1, gw1_2, gb1_2, hg);
    k_out<<<(OUT_TOTAL + 63) / 64, 256, 0, stream>>>(hg, gw2_0, gb2_0, gw2_1, gb2_1,
                                                     gw2_2, gb2_2, (float*)d_out);
}